// Round 3
// baseline (545.715 us; speedup 1.0000x reference)
//
#include <hip/hip_runtime.h>

// NegativeKLDiv: bs=2048, n1=n2=4, d=4608, fp32.
// out[b,i,j] = cross[b,i,j] - ent[b,i]
//   ent[b,i]     = sum_d p*log(p+eps),  p = input1*mask1
//   cross[b,i,j] = sum_d p_i * log(q_j+eps), q = input2*mask2
//
// R1: VGPR=36, 181us @1.67TB/s -> latency-bound (too few loads in flight).
// R2: 16-load batch spilled (WRITE_SIZE 108MB) -> 203us. Spills, not occupancy,
//     are the failure mode.
// R3: wave-per-q-row. 5 accumulators + 10 named-field loads, A/B double
//     buffer, template<J> for compile-time ent row select. No indexed arrays.

constexpr int   D   = 4608;
constexpr int   DV  = D / 4;      // 1152 float4 per row = 64 lanes * 18 iters
constexpr int   NT  = 256;        // 4 waves: wave j owns q-row j
constexpr float EPS = 1e-9f;

struct Buf {
    float4 c, mc, a0, ma0, a1, ma1, a2, ma2, a3, ma3;
};

__device__ __forceinline__ void load10(Buf& B,
        const float4* __restrict__ p1, const float4* __restrict__ g1,
        const float4* __restrict__ q2, const float4* __restrict__ g2, int v)
{
    B.c   = q2[v];
    B.mc  = g2[v];
    B.a0  = p1[v];
    B.ma0 = g1[v];
    B.a1  = p1[v + DV];
    B.ma1 = g1[v + DV];
    B.a2  = p1[v + 2 * DV];
    B.ma2 = g1[v + 2 * DV];
    B.a3  = p1[v + 3 * DV];
    B.ma3 = g1[v + 3 * DV];
}

__device__ __forceinline__ float4 mul4(float4 a, float4 b) {
    return make_float4(a.x * b.x, a.y * b.y, a.z * b.z, a.w * b.w);
}
__device__ __forceinline__ float4 log4e(float4 a) {
    return make_float4(__logf(a.x + EPS), __logf(a.y + EPS),
                       __logf(a.z + EPS), __logf(a.w + EPS));
}
__device__ __forceinline__ float dot4(float4 a, float4 b) {
    return a.x * b.x + a.y * b.y + a.z * b.z + a.w * b.w;
}

template<int J>
__device__ __forceinline__ void computeB(const Buf& B, float* cr, float& ent)
{
    float4 lq = log4e(mul4(B.c, B.mc));
    float4 p0 = mul4(B.a0, B.ma0);
    float4 p1 = mul4(B.a1, B.ma1);
    float4 p2 = mul4(B.a2, B.ma2);
    float4 p3 = mul4(B.a3, B.ma3);
    cr[0] += dot4(p0, lq);
    cr[1] += dot4(p1, lq);
    cr[2] += dot4(p2, lq);
    cr[3] += dot4(p3, lq);
    const float4 pj = (J == 0) ? p0 : (J == 1) ? p1 : (J == 2) ? p2 : p3;
    ent += dot4(pj, log4e(pj));
}

template<int J>
__device__ __forceinline__ void waveBody(
        const float4* __restrict__ p1, const float4* __restrict__ g1,
        const float4* __restrict__ q2, const float4* __restrict__ g2,
        int lane, float* cr, float& ent)
{
    Buf A, B;
    int v = lane;
    load10(A, p1, g1, q2, g2, v);
    for (int k = 0; k < 18; k += 2) {
        load10(B, p1, g1, q2, g2, v + 64);
        computeB<J>(A, cr, ent);
        if (k + 2 < 18) load10(A, p1, g1, q2, g2, v + 128);
        computeB<J>(B, cr, ent);
        v += 128;
    }
}

__global__ __launch_bounds__(NT, 4)   // allow up to 128 VGPRs
void nkld_kernel(const float* __restrict__ in1, const float* __restrict__ m1,
                 const float* __restrict__ in2, const float* __restrict__ m2,
                 float* __restrict__ out)
{
    const int b    = blockIdx.x;      // one block per batch
    const int tid  = threadIdx.x;
    const int wave = tid >> 6;        // q-row j
    const int lane = tid & 63;

    const size_t base = (size_t)b * 4 * D;
    const float4* p1 = reinterpret_cast<const float4*>(in1 + base);
    const float4* g1 = reinterpret_cast<const float4*>(m1  + base);
    const float4* q2 = reinterpret_cast<const float4*>(in2 + base) + (size_t)wave * DV;
    const float4* g2 = reinterpret_cast<const float4*>(m2  + base) + (size_t)wave * DV;

    float cr[4] = {0.f, 0.f, 0.f, 0.f};   // cross[i][j=wave], i=0..3
    float ent = 0.f;                       // ent[j=wave]

    switch (wave) {
        case 0: waveBody<0>(p1, g1, q2, g2, lane, cr, ent); break;
        case 1: waveBody<1>(p1, g1, q2, g2, lane, cr, ent); break;
        case 2: waveBody<2>(p1, g1, q2, g2, lane, cr, ent); break;
        case 3: waveBody<3>(p1, g1, q2, g2, lane, cr, ent); break;
    }

    // intra-wave reduce 5 scalars (static indices only)
    #pragma unroll
    for (int off = 32; off > 0; off >>= 1) {
        cr[0] += __shfl_down(cr[0], off, 64);
        cr[1] += __shfl_down(cr[1], off, 64);
        cr[2] += __shfl_down(cr[2], off, 64);
        cr[3] += __shfl_down(cr[3], off, 64);
        ent   += __shfl_down(ent,   off, 64);
    }

    __shared__ float ent_s[4];
    __shared__ float cr_s[4][4];          // [j][i]
    if (lane == 0) {
        ent_s[wave]   = ent;
        cr_s[wave][0] = cr[0];
        cr_s[wave][1] = cr[1];
        cr_s[wave][2] = cr[2];
        cr_s[wave][3] = cr[3];
    }
    __syncthreads();

    if (tid < 16) {
        const int i = tid >> 2, j = tid & 3;
        out[(size_t)b * 16 + tid] = cr_s[j][i] - ent_s[i];  // cross - ent
    }
}

extern "C" void kernel_launch(void* const* d_in, const int* in_sizes, int n_in,
                              void* d_out, int out_size, void* d_ws, size_t ws_size,
                              hipStream_t stream) {
    const float* in1 = (const float*)d_in[0];
    const float* m1  = (const float*)d_in[1];
    const float* in2 = (const float*)d_in[2];
    const float* m2  = (const float*)d_in[3];
    float* out = (float*)d_out;
    nkld_kernel<<<dim3(2048), dim3(NT), 0, stream>>>(in1, m1, in2, m2, out);
}

// Round 5
// 478.417 us; speedup vs baseline: 1.1407x; 1.1407x over previous
//
#include <hip/hip_runtime.h>

// NegativeKLDiv: bs=2048, n1=n2=4, d=4608, fp32.
// out[b,i,j] = cross[b,i,j] - ent[b,i]
//   ent[b,i]     = sum_d p*log(p+eps),  p = input1*mask1
//   cross[b,i,j] = sum_d p_i * log(q_j+eps), q = input2*mask2
//
// R1: VGPR=36, 181us, delivered 3.34 TB/s (FETCH 295MB, rest L3). No spill.
// R2: 16-load batch -> spill (WRITE 108MB), 203us.
// R3: wave-per-q-row dbuf -> STILL spilled (VGPR capped 64, WRITE 269MB), 242us.
// R4: GPU acquisition timeout — no data. Resubmitting unchanged.
// R5(=R4): amdgpu_waves_per_eu(2,4) to unlock the VGPR budget (launch_bounds'
//     2nd arg did not). Distinguishes T-MLP (latency, expect ~100us) from
//     T-wall (~3.4 TB/s read ceiling, expect ~180us).

constexpr int   D   = 4608;
constexpr int   DV  = D / 4;      // 1152 float4 per row = 64 lanes * 18 iters
constexpr int   NT  = 256;        // 4 waves: wave j owns q-row j
constexpr float EPS = 1e-9f;

struct Buf {
    float4 c, mc, a0, ma0, a1, ma1, a2, ma2, a3, ma3;
};

__device__ __forceinline__ void load10(Buf& B,
        const float4* __restrict__ p1, const float4* __restrict__ g1,
        const float4* __restrict__ q2, const float4* __restrict__ g2, int v)
{
    B.c   = q2[v];
    B.mc  = g2[v];
    B.a0  = p1[v];
    B.ma0 = g1[v];
    B.a1  = p1[v + DV];
    B.ma1 = g1[v + DV];
    B.a2  = p1[v + 2 * DV];
    B.ma2 = g1[v + 2 * DV];
    B.a3  = p1[v + 3 * DV];
    B.ma3 = g1[v + 3 * DV];
}

__device__ __forceinline__ float4 mul4(float4 a, float4 b) {
    return make_float4(a.x * b.x, a.y * b.y, a.z * b.z, a.w * b.w);
}
__device__ __forceinline__ float4 log4e(float4 a) {
    return make_float4(__logf(a.x + EPS), __logf(a.y + EPS),
                       __logf(a.z + EPS), __logf(a.w + EPS));
}
__device__ __forceinline__ float dot4(float4 a, float4 b) {
    return a.x * b.x + a.y * b.y + a.z * b.z + a.w * b.w;
}

template<int J>
__device__ __forceinline__ void computeB(const Buf& B, float* cr, float& ent)
{
    float4 lq = log4e(mul4(B.c, B.mc));
    float4 p0 = mul4(B.a0, B.ma0);
    float4 p1 = mul4(B.a1, B.ma1);
    float4 p2 = mul4(B.a2, B.ma2);
    float4 p3 = mul4(B.a3, B.ma3);
    cr[0] += dot4(p0, lq);
    cr[1] += dot4(p1, lq);
    cr[2] += dot4(p2, lq);
    cr[3] += dot4(p3, lq);
    const float4 pj = (J == 0) ? p0 : (J == 1) ? p1 : (J == 2) ? p2 : p3;
    ent += dot4(pj, log4e(pj));
}

template<int J>
__device__ __forceinline__ void waveBody(
        const float4* __restrict__ p1, const float4* __restrict__ g1,
        const float4* __restrict__ q2, const float4* __restrict__ g2,
        int lane, float* cr, float& ent)
{
    Buf A, B;
    int v = lane;
    load10(A, p1, g1, q2, g2, v);
    for (int k = 0; k < 18; k += 2) {
        load10(B, p1, g1, q2, g2, v + 64);
        computeB<J>(A, cr, ent);
        if (k + 2 < 18) load10(A, p1, g1, q2, g2, v + 128);
        computeB<J>(B, cr, ent);
        v += 128;
    }
}

__global__ __launch_bounds__(NT)
__attribute__((amdgpu_waves_per_eu(2, 4)))   // regalloc budget up to 256 VGPR
void nkld_kernel(const float* __restrict__ in1, const float* __restrict__ m1,
                 const float* __restrict__ in2, const float* __restrict__ m2,
                 float* __restrict__ out)
{
    const int b    = blockIdx.x;      // one block per batch
    const int tid  = threadIdx.x;
    const int wave = tid >> 6;        // q-row j
    const int lane = tid & 63;

    const size_t base = (size_t)b * 4 * D;
    const float4* p1 = reinterpret_cast<const float4*>(in1 + base);
    const float4* g1 = reinterpret_cast<const float4*>(m1  + base);
    const float4* q2 = reinterpret_cast<const float4*>(in2 + base) + (size_t)wave * DV;
    const float4* g2 = reinterpret_cast<const float4*>(m2  + base) + (size_t)wave * DV;

    float cr[4] = {0.f, 0.f, 0.f, 0.f};   // cross[i][j=wave], i=0..3
    float ent = 0.f;                       // ent[j=wave]

    switch (wave) {
        case 0: waveBody<0>(p1, g1, q2, g2, lane, cr, ent); break;
        case 1: waveBody<1>(p1, g1, q2, g2, lane, cr, ent); break;
        case 2: waveBody<2>(p1, g1, q2, g2, lane, cr, ent); break;
        case 3: waveBody<3>(p1, g1, q2, g2, lane, cr, ent); break;
    }

    // intra-wave reduce 5 scalars (static indices only)
    #pragma unroll
    for (int off = 32; off > 0; off >>= 1) {
        cr[0] += __shfl_down(cr[0], off, 64);
        cr[1] += __shfl_down(cr[1], off, 64);
        cr[2] += __shfl_down(cr[2], off, 64);
        cr[3] += __shfl_down(cr[3], off, 64);
        ent   += __shfl_down(ent,   off, 64);
    }

    __shared__ float ent_s[4];
    __shared__ float cr_s[4][4];          // [j][i]
    if (lane == 0) {
        ent_s[wave]   = ent;
        cr_s[wave][0] = cr[0];
        cr_s[wave][1] = cr[1];
        cr_s[wave][2] = cr[2];
        cr_s[wave][3] = cr[3];
    }
    __syncthreads();

    if (tid < 16) {
        const int i = tid >> 2, j = tid & 3;
        out[(size_t)b * 16 + tid] = cr_s[j][i] - ent_s[i];  // cross - ent
    }
}

extern "C" void kernel_launch(void* const* d_in, const int* in_sizes, int n_in,
                              void* d_out, int out_size, void* d_ws, size_t ws_size,
                              hipStream_t stream) {
    const float* in1 = (const float*)d_in[0];
    const float* m1  = (const float*)d_in[1];
    const float* in2 = (const float*)d_in[2];
    const float* m2  = (const float*)d_in[3];
    float* out = (float*)d_out;
    nkld_kernel<<<dim3(2048), dim3(NT), 0, stream>>>(in1, m1, in2, m2, out);
}

// Round 6
// 473.508 us; speedup vs baseline: 1.1525x; 1.0104x over previous
//
#include <hip/hip_runtime.h>
#include <stdint.h>

// NegativeKLDiv: bs=2048, n1=n2=4, d=4608, fp32.
// out[b,i,j] = cross[b,i,j] - ent[b,i]
//
// R1: reg-loads shallow MLP: 181us, 3.34 TB/s delivered.
// R5: reg-loads deep MLP (10 in flight, no spill): 172us, 3.50 TB/s.
//     -> per-CU outstanding-read limit (~4KB MSHR) theory; VGPR-return path walls.
// R6: PROBE the global_load_lds DMA path: stage all 4 arrays to LDS in
//     18 chunks/batch, double-buffered, counted vmcnt + raw s_barrier
//     (prefetch stays in flight across barriers). If this also pins at
//     ~3.5 TB/s the wall is universal -> roofline.

constexpr int   NT  = 256;
constexpr float EPS = 1e-9f;
// 4608 floats/row = 1152 float4/row = 18 chunks of 64 quads

__device__ __forceinline__ float4 mul4(float4 a, float4 b) {
    return make_float4(a.x*b.x, a.y*b.y, a.z*b.z, a.w*b.w);
}
__device__ __forceinline__ float4 log4e(float4 a) {
    return make_float4(__logf(a.x+EPS), __logf(a.y+EPS),
                       __logf(a.z+EPS), __logf(a.w+EPS));
}
__device__ __forceinline__ float dot4(float4 a, float4 b) {
    return a.x*b.x + a.y*b.y + a.z*b.z + a.w*b.w;
}

__device__ __forceinline__ void gll16(const float4* g, float4* l) {
    __builtin_amdgcn_global_load_lds(
        (const __attribute__((address_space(1))) uint32_t*)(const void*)g,
        (__attribute__((address_space(3))) uint32_t*)(void*)l,
        16 /*bytes, literal*/, 0, 0);
}

__global__ __launch_bounds__(NT)
void nkld_kernel(const float4* __restrict__ A0, const float4* __restrict__ A1,
                 const float4* __restrict__ A2, const float4* __restrict__ A3,
                 float* __restrict__ out)
{
    // LDS: 2 x 16KB stage buffers [a*256 + r*64 + pos] + 4KB lq + reduce
    __shared__ float4 buf[2][1024];
    __shared__ float4 slq[256];
    __shared__ float  ent_s[4];
    __shared__ float  cr_s[4][4];

    const int b    = blockIdx.x;          // one block per batch
    const int tid  = threadIdx.x;
    const int w    = tid >> 6;            // wave = row index r
    const int lane = tid & 63;
    // quad offset of (batch b, row w, pos lane) in any of the 4 arrays
    const int soff = b * 4608 + w * 1152 + lane;

    float cr0=0.f, cr1=0.f, cr2=0.f, cr3=0.f, ent=0.f;

    // prologue: stage chunk 0 (each thread: 4 x global_load_lds, 16B each)
    gll16(A0 + soff, &buf[0][tid]);
    gll16(A1 + soff, &buf[0][256 + tid]);
    gll16(A2 + soff, &buf[0][512 + tid]);
    gll16(A3 + soff, &buf[0][768 + tid]);
    asm volatile("s_waitcnt vmcnt(0)" ::: "memory");
    __builtin_amdgcn_s_barrier();

    int cur = 0;
    #pragma unroll 1
    for (int c = 0; c < 18; ++c) {
        // issue next chunk's DMA into the other buffer (stays in flight
        // through the compute below and across the barrier)
        if (c + 1 < 18) {
            const int o = soff + (c + 1) * 64;
            float4* dst = buf[cur ^ 1];
            gll16(A0 + o, dst + tid);
            gll16(A1 + o, dst + 256 + tid);
            gll16(A2 + o, dst + 512 + tid);
            gll16(A3 + o, dst + 768 + tid);
        }
        // lq pass: thread t computes log(q*mq+eps) for quad t of this chunk
        {
            float4 q  = buf[cur][512 + tid];
            float4 mq = buf[cur][768 + tid];
            slq[tid] = log4e(mul4(q, mq));
        }
        asm volatile("s_waitcnt lgkmcnt(0)" ::: "memory");
        __builtin_amdgcn_s_barrier();
        // compute: wave w owns p-row w; reads all 4 lq rows from LDS
        {
            float4 p = mul4(buf[cur][w*64 + lane], buf[cur][256 + w*64 + lane]);
            ent += dot4(p, log4e(p));
            cr0 += dot4(p, slq[lane]);
            cr1 += dot4(p, slq[ 64 + lane]);
            cr2 += dot4(p, slq[128 + lane]);
            cr3 += dot4(p, slq[192 + lane]);
        }
        // drain my prefetch (vm) + my LDS reads (lgkm), then block barrier:
        // buf[cur^1] fully staged, slq free to overwrite next iteration
        asm volatile("s_waitcnt vmcnt(0) lgkmcnt(0)" ::: "memory");
        __builtin_amdgcn_s_barrier();
        cur ^= 1;
    }

    // intra-wave reduce (static names only)
    #pragma unroll
    for (int off = 32; off > 0; off >>= 1) {
        cr0 += __shfl_down(cr0, off, 64);
        cr1 += __shfl_down(cr1, off, 64);
        cr2 += __shfl_down(cr2, off, 64);
        cr3 += __shfl_down(cr3, off, 64);
        ent += __shfl_down(ent, off, 64);
    }
    if (lane == 0) {
        ent_s[w]   = ent;      // ent[i=w]
        cr_s[w][0] = cr0;      // cross[i=w][j]
        cr_s[w][1] = cr1;
        cr_s[w][2] = cr2;
        cr_s[w][3] = cr3;
    }
    __syncthreads();
    if (tid < 16) {
        const int i = tid >> 2, j = tid & 3;
        out[(size_t)b * 16 + tid] = cr_s[i][j] - ent_s[i];  // cross - ent
    }
}

extern "C" void kernel_launch(void* const* d_in, const int* in_sizes, int n_in,
                              void* d_out, int out_size, void* d_ws, size_t ws_size,
                              hipStream_t stream) {
    const float4* A0 = (const float4*)d_in[0];  // input1
    const float4* A1 = (const float4*)d_in[1];  // mask1
    const float4* A2 = (const float4*)d_in[2];  // input2
    const float4* A3 = (const float4*)d_in[3];  // mask2
    float* out = (float*)d_out;
    nkld_kernel<<<dim3(2048), dim3(NT), 0, stream>>>(A0, A1, A2, A3, out);
}